// Round 1
// baseline (2028.308 us; speedup 1.0000x reference)
//
#include <hip/hip_runtime.h>
#include <math.h>

#define HH 4096
#define WW 4096

// Per-cell decision threshold k: new_label = (ns >= k), k in {0..5}.
// Built once in float64 replicating the reference comparison order:
//   cost1 = u1 + 0.5*(ncnt - ns), cost0 = u0 + 0.5*ns, new = cost1 < cost0
// Monotone in ns => threshold representation is exact.
__global__ void init_kernel(const float* __restrict__ probs,
                            unsigned char* __restrict__ kthr,
                            unsigned char* __restrict__ labels) {
    int idx = blockIdx.x * blockDim.x + threadIdx.x;
    if (idx >= HH * WW) return;
    int i = idx / WW;
    int j = idx - i * WW;
    float p = probs[idx];
    double pd = (double)p;
    double u1 = -log(pd + 1e-6);          // -log(p + EPS)
    double u0 = -log1p(-(pd - 1e-6));     // -log1p(-(p - EPS))
    int ncnt = 4 - (i == 0) - (i == HH - 1) - (j == 0) - (j == WW - 1);
    int k = 5;                             // never flips to 1
    for (int ns = 0; ns <= 4; ++ns) {
        double cost1 = u1 + 0.5 * (double)(ncnt - ns);
        double cost0 = u0 + 0.5 * (double)ns;
        if (cost1 < cost0) { k = ns; break; }
    }
    kthr[idx] = (unsigned char)k;
    labels[idx] = (p > 0.5f) ? 1 : 0;      // exact decision, fp32 compare
}

// One checkerboard half-sweep: update cells with (i+j)%2 == parity.
__global__ void sweep_kernel(const unsigned char* __restrict__ kthr,
                             unsigned char* __restrict__ labels,
                             int parity) {
    const int WH = WW / 2;
    int tid = blockIdx.x * blockDim.x + threadIdx.x;
    if (tid >= HH * WH) return;
    int i = tid / WH;
    int jh = tid - i * WH;
    int j = 2 * jh + ((i + parity) & 1);
    int idx = i * WW + j;
    int ns = 0;
    if (i > 0)      ns += labels[idx - WW];
    if (i < HH - 1) ns += labels[idx + WW];
    if (j > 0)      ns += labels[idx - 1];
    if (j < WW - 1) ns += labels[idx + 1];
    labels[idx] = (ns >= (int)kthr[idx]) ? 1 : 0;
}

__global__ void final_kernel(const unsigned char* __restrict__ labels,
                             float* __restrict__ out) {
    int idx = blockIdx.x * blockDim.x + threadIdx.x;
    if (idx < HH * WW) out[idx] = (float)labels[idx];
}

extern "C" void kernel_launch(void* const* d_in, const int* in_sizes, int n_in,
                              void* d_out, int out_size, void* d_ws, size_t ws_size,
                              hipStream_t stream) {
    const float* probs = (const float*)d_in[0];
    float* out = (float*)d_out;
    unsigned char* kthr = (unsigned char*)d_ws;           // 16 MB
    unsigned char* labels = kthr + (size_t)HH * WW;       // 16 MB

    const int n = HH * WW;
    init_kernel<<<(n + 255) / 256, 256, 0, stream>>>(probs, kthr, labels);

    const int nhalf = HH * (WW / 2);
    for (int s = 0; s < 60; ++s) {   // N_SWEEPS=30, parities [0,1]*30
        sweep_kernel<<<(nhalf + 255) / 256, 256, 0, stream>>>(kthr, labels, s & 1);
    }

    final_kernel<<<(n + 255) / 256, 256, 0, stream>>>(labels, out);
}

// Round 2
// 340.264 us; speedup vs baseline: 5.9610x; 5.9610x over previous
//
#include <hip/hip_runtime.h>
#include <math.h>

#define HH 4096
#define WW 4096
#define WPR 64                 // 64-bit words per row (4096 bits)
#define NWORDS (HH * WPR)      // 262144 words total
typedef unsigned long long u64;

// fp64 decision, EXACTLY as the round-1 kernel that scored absmax=0:
//   u1 = -log(pd + 1e-6); u0 = -log1p(-(pd - 1e-6));
//   cost1 = u1 + 0.5*(ncnt-ns); cost0 = u0 + 0.5*ns; return cost1 < cost0
__device__ __forceinline__ bool decision(float p, int ncnt, int ns) {
    double pd = (double)p;
    double u1 = -log(pd + 1e-6);
    double u0 = -log1p(-(pd - 1e-6));
    double cost1 = u1 + 0.5 * (double)(ncnt - ns);
    double cost0 = u0 + 0.5 * (double)ns;
    return cost1 < cost0;
}

// For each (ncnt in {2,3,4}, ns in {0..4}): binary-search the minimal fp32
// p in [0,1] where decision() becomes true. Monotone (weakly) in p, so
// comparing p < C reproduces the fp64 decision bit-exactly for fp32 p.
__global__ void setup_kernel(float* __restrict__ C) {
    int t = threadIdx.x;
    if (t >= 15) return;
    int ncnt = 2 + t / 5;
    int ns = t % 5;
    // positive fp32 ordering == uint ordering; search [0.0f, 1.0f]
    unsigned lo = 0u;               // bits of 0.0f  (decision false there)
    unsigned hi = 0x3F800000u;      // bits of 1.0f  (decision true there)
    for (int it = 0; it < 32 && hi - lo > 1; ++it) {
        unsigned mid = lo + (hi - lo) / 2;
        float pm = __uint_as_float(mid);
        if (decision(pm, ncnt, ns)) hi = mid; else lo = mid;
    }
    C[t] = __uint_as_float(hi);     // minimal p with decision true
}

// Build bit-packed labels + 3 threshold bit-planes via wave ballots.
// k = count of ns in 0..4 with (p < C[ncnt][ns])  (k=5 => never flips to 1)
__global__ void init_bits(const float* __restrict__ probs,
                          const float* __restrict__ C,
                          u64* __restrict__ L, u64* __restrict__ K0,
                          u64* __restrict__ K1, u64* __restrict__ K2) {
    const int WPW = 4;  // words per wave
    int gwave = (blockIdx.x * blockDim.x + threadIdx.x) >> 6;
    int lane = threadIdx.x & 63;
    int w0 = gwave * WPW;
    for (int q = 0; q < WPW; ++q) {
        int w = w0 + q;
        if (w >= NWORDS) return;
        long cell = ((long)w << 6) + lane;
        int i = (int)(cell >> 12);
        int j = (int)(cell & (WW - 1));
        float p = probs[cell];
        int ncnt = 4 - (i == 0) - (i == HH - 1) - (j == 0) - (j == WW - 1);
        const float* Cr = C + (ncnt - 2) * 5;
        int k = (p < Cr[0]) + (p < Cr[1]) + (p < Cr[2]) + (p < Cr[3]) + (p < Cr[4]);
        u64 lb = __ballot(p > 0.5f);
        u64 b0 = __ballot(k & 1);
        u64 b1 = __ballot(k & 2);
        u64 b2 = __ballot(k & 4);
        if (lane == 0) { L[w] = lb; K0[w] = b0; K1[w] = b1; K2[w] = b2; }
    }
}

// One checkerboard half-sweep over the bit-packed labels, in place.
// Safe: writes change only parity-P bits; concurrent readers use only
// parity-(1-P) bits of neighbor words (8B-aligned stores are atomic).
__global__ void sweep_bits(u64* __restrict__ L,
                           const u64* __restrict__ K0,
                           const u64* __restrict__ K1,
                           const u64* __restrict__ K2, int parity) {
    int w = blockIdx.x * blockDim.x + threadIdx.x;
    if (w >= NWORDS) return;
    int i = w >> 6;            // row
    int wc = w & (WPR - 1);    // word-column
    u64 cur = L[w];
    u64 up    = (i > 0)        ? L[w - WPR] : 0;
    u64 down  = (i < HH - 1)   ? L[w + WPR] : 0;
    u64 prevw = (wc > 0)       ? L[w - 1]   : 0;
    u64 nextw = (wc < WPR - 1) ? L[w + 1]   : 0;
    u64 lv = (cur << 1) | (prevw >> 63);   // left-neighbor labels, per bit
    u64 rv = (cur >> 1) | (nextw << 63);   // right-neighbor labels
    // bit-sliced ns = up+down+lv+rv  (3 planes n2:n1:n0)
    u64 s  = up ^ down,  c1 = up & down;
    u64 t  = lv ^ rv,    c2 = lv & rv;
    u64 n0 = s ^ t;
    u64 c3 = s & t;
    u64 n1 = c1 ^ c2 ^ c3;
    u64 n2 = (c1 & c2) | (c3 & (c1 ^ c2));          // majority(c1,c2,c3)
    u64 k0 = K0[w], k1 = K1[w], k2 = K2[w];
    // 3-bit unsigned compare: ge = (ns >= k), per bit position
    u64 ge = (n2 & ~k2) |
             (~(n2 ^ k2) & ((n1 & ~k1) |
                            (~(n1 ^ k1) & (n0 | ~k0))));
    // checkerboard: update columns j with (i+j)%2==parity; j%2 == bit%2
    u64 mask = ((i + parity) & 1) ? 0xAAAAAAAAAAAAAAAAull
                                  : 0x5555555555555555ull;
    L[w] = (ge & mask) | (cur & ~mask);
}

// Expand bitmap to float32 output (4 cells / thread, float4 stores).
__global__ void final_bits(const u64* __restrict__ L, float* __restrict__ out) {
    int tid = blockIdx.x * blockDim.x + threadIdx.x;       // 4.19M threads
    if (tid >= (HH * WW) / 4) return;
    u64 word = L[tid >> 4];
    int sh = (tid & 15) * 4;
    unsigned bits = (unsigned)(word >> sh) & 0xFu;
    float4 v;
    v.x = (bits & 1u) ? 1.0f : 0.0f;
    v.y = (bits & 2u) ? 1.0f : 0.0f;
    v.z = (bits & 4u) ? 1.0f : 0.0f;
    v.w = (bits & 8u) ? 1.0f : 0.0f;
    ((float4*)out)[tid] = v;
}

extern "C" void kernel_launch(void* const* d_in, const int* in_sizes, int n_in,
                              void* d_out, int out_size, void* d_ws, size_t ws_size,
                              hipStream_t stream) {
    const float* probs = (const float*)d_in[0];
    float* out = (float*)d_out;
    char* ws = (char*)d_ws;
    u64* L  = (u64*)(ws);                       // 2 MB
    u64* K0 = (u64*)(ws + (2u << 20));          // 2 MB
    u64* K1 = (u64*)(ws + (4u << 20));          // 2 MB
    u64* K2 = (u64*)(ws + (6u << 20));          // 2 MB
    float* C = (float*)(ws + (8u << 20));       // 15 floats

    setup_kernel<<<1, 64, 0, stream>>>(C);

    // init: 4 words/wave, 4 waves/block -> NWORDS/16 = 16384 blocks
    init_bits<<<NWORDS / 16, 256, 0, stream>>>(probs, C, L, K0, K1, K2);

    for (int s = 0; s < 60; ++s)   // N_SWEEPS=30, parities [0,1]*30
        sweep_bits<<<NWORDS / 256, 256, 0, stream>>>(L, K0, K1, K2, s & 1);

    final_bits<<<(HH * WW / 4) / 256, 256, 0, stream>>>(L, out);
}

// Round 3
// 265.390 us; speedup vs baseline: 7.6428x; 1.2821x over previous
//
#include <hip/hip_runtime.h>
#include <math.h>

#define HH 4096
#define WW 4096
#define WPR 64                 // 64-bit words per row
#define NWORDS (HH * WPR)      // 262144
typedef unsigned long long u64;

#define TILE_R 128             // interior rows per block
#define HALO_R 60              // vertical halo (= #half-sweeps)
#define REG_R  248             // TILE_R + 2*HALO_R
#define REG_WC 10              // 8 interior word-cols + 1 halo each side
#define RWORDS (REG_R * REG_WC) // 2480
#define WPT    10              // ceil(RWORDS / 256)
#define NSWEEP 60

// fp64 decision, EXACTLY as the round-1 kernel that scored absmax=0.
__device__ __forceinline__ bool decision(float p, int ncnt, int ns) {
    double pd = (double)p;
    double u1 = -log(pd + 1e-6);
    double u0 = -log1p(-(pd - 1e-6));
    double cost1 = u1 + 0.5 * (double)(ncnt - ns);
    double cost0 = u0 + 0.5 * (double)ns;
    return cost1 < cost0;
}

// Binary-search minimal fp32 p where decision() is true (monotone in p).
__global__ void setup_kernel(float* __restrict__ C) {
    int t = threadIdx.x;
    if (t >= 15) return;
    int ncnt = 2 + t / 5;
    int ns = t % 5;
    unsigned lo = 0u, hi = 0x3F800000u;   // [0.0f, 1.0f] in bit-space
    for (int it = 0; it < 32 && hi - lo > 1; ++it) {
        unsigned mid = lo + (hi - lo) / 2;
        if (decision(__uint_as_float(mid), ncnt, ns)) hi = mid; else lo = mid;
    }
    C[t] = __uint_as_float(hi);
}

// Pack labels (1 bit) + threshold planes k0/k1/k2 (3 bits) via wave ballots.
// Kp layout: 4 u64 per word index (k0,k1,k2,pad) for vectorized reload.
__global__ void init_bits(const float* __restrict__ probs,
                          const float* __restrict__ C,
                          u64* __restrict__ L, u64* __restrict__ Kp) {
    int gwave = (blockIdx.x * blockDim.x + threadIdx.x) >> 6;
    int lane = threadIdx.x & 63;
    int w0 = gwave * 4;
#pragma unroll
    for (int q = 0; q < 4; ++q) {
        int w = w0 + q;                    // grid exactly covers NWORDS
        long cell = ((long)w << 6) + lane;
        int i = (int)(cell >> 12);
        int j = (int)(cell & (WW - 1));
        float p = probs[cell];
        int ncnt = 4 - (i == 0) - (i == HH - 1) - (j == 0) - (j == WW - 1);
        const float* Cr = C + (ncnt - 2) * 5;
        int k = (p < Cr[0]) + (p < Cr[1]) + (p < Cr[2]) + (p < Cr[3]) + (p < Cr[4]);
        u64 lb = __ballot(p > 0.5f);
        u64 b0 = __ballot(k & 1);
        u64 b1 = __ballot(k & 2);
        u64 b2 = __ballot(k & 4);
        if (lane == 0) {
            L[w] = lb;
            u64* kp = Kp + 4ll * w;
            kp[0] = b0; kp[1] = b1; kp[2] = b2;
        }
    }
}

// All 60 half-sweeps in one launch: halo-redundant LDS tiles, k-planes in
// registers, trapezoid update bounds, fused float4 output expansion.
__global__ __launch_bounds__(256, 1)
void fused_sweeps(const u64* __restrict__ L, const u64* __restrict__ Kp,
                  float* __restrict__ out) {
    __shared__ u64 SL[RWORDS];
    const int tid = threadIdx.x;
    const int tr = blockIdx.x >> 3;          // 0..31 tile row
    const int tc = blockIdx.x & 7;           // 0..7  tile col
    const int r0 = tr * TILE_R - HALO_R;     // global row of region row 0
    const int wc0 = tc * 8 - 1;              // global word-col of region col 0

    u64 cur[WPT], k0[WPT], k1[WPT], k2[WPT];
    int rr[WPT], cc[WPT];
#pragma unroll
    for (int m = 0; m < WPT; ++m) {
        int idx = tid + 256 * m;
        u64 l = 0, a = ~0ull, b = ~0ull, c2 = ~0ull;   // outside: label 0, k=7
        int r = 0, c = 0;
        if (idx < RWORDS) {
            r = idx / REG_WC;
            c = idx - r * REG_WC;
            int g = r0 + r, wc = wc0 + c;
            if (g >= 0 && g < HH && wc >= 0 && wc < WPR) {
                size_t w = (size_t)g * WPR + wc;
                l = L[w];
                const u64* kp = Kp + 4 * w;
                a = kp[0]; b = kp[1]; c2 = kp[2];
            }
            SL[idx] = l;
        }
        cur[m] = l; k0[m] = a; k1[m] = b; k2[m] = c2;
        rr[m] = r; cc[m] = c;
    }
    __syncthreads();

    for (int s = 0; s < NSWEEP; ++s) {
        const u64 flip = (s & 1) ? ~0ull : 0ull;
        const int rlo = s + 1, rhi = REG_R - 1 - s;   // trapezoid bounds
#pragma unroll
        for (int m = 0; m < WPT; ++m) {
            int idx = tid + 256 * m;
            int r = rr[m];
            if (idx < RWORDS && r >= rlo && r < rhi) {
                int c = cc[m];
                u64 center = cur[m];
                u64 up = SL[idx - REG_WC], dn = SL[idx + REG_WC];
                u64 pw = (c > 0) ? SL[idx - 1] : 0ull;
                u64 nw = (c < REG_WC - 1) ? SL[idx + 1] : 0ull;
                u64 lv = (center << 1) | (pw >> 63);
                u64 rv = (center >> 1) | (nw << 63);
                // bit-sliced ns = up+dn+lv+rv (planes n2:n1:n0)
                u64 sxy = up ^ dn, c1 = up & dn;
                u64 txy = lv ^ rv, cA = lv & rv;
                u64 n0 = sxy ^ txy, c3 = sxy & txy;
                u64 n1 = c1 ^ cA ^ c3;
                u64 n2 = (c1 & cA) | (c3 & (c1 ^ cA));
                // ge = (ns >= k), 3-bit unsigned compare
                u64 ge = (n2 & ~k2[m]) |
                         (~(n2 ^ k2[m]) & ((n1 & ~k1[m]) |
                                           (~(n1 ^ k1[m]) & (n0 | ~k0[m]))));
                u64 base = ((r0 + r) & 1) ? 0xAAAAAAAAAAAAAAAAull
                                          : 0x5555555555555555ull;
                u64 mask = base ^ flip;
                u64 nv = (ge & mask) | (center & ~mask);
                cur[m] = nv;
                SL[idx] = nv;   // race-free: writes touch only parity-s bits
            }
        }
        __syncthreads();
    }

    // Expand interior (128 rows x 512 bits) to float4 output.
#pragma unroll 8
    for (int m = 0; m < 64; ++m) {
        int idx = tid + 256 * m;          // 0..16383 float4s
        int ri = idx >> 7;                // interior row 0..127
        int q = idx & 127;                // float4 within row
        u64 word = SL[(HALO_R + ri) * REG_WC + 1 + (q >> 4)];
        unsigned bits = (unsigned)(word >> ((q & 15) * 4)) & 0xFu;
        float4 v;
        v.x = (float)(bits & 1u);
        v.y = (float)((bits >> 1) & 1u);
        v.z = (float)((bits >> 2) & 1u);
        v.w = (float)((bits >> 3) & 1u);
        int g = tr * TILE_R + ri;
        ((float4*)out)[(size_t)g * (WW / 4) + (wc0 + 1) * 16 + q] = v;
    }
}

extern "C" void kernel_launch(void* const* d_in, const int* in_sizes, int n_in,
                              void* d_out, int out_size, void* d_ws, size_t ws_size,
                              hipStream_t stream) {
    const float* probs = (const float*)d_in[0];
    float* out = (float*)d_out;
    char* ws = (char*)d_ws;
    u64* L  = (u64*)(ws);                        // 2 MB
    u64* Kp = (u64*)(ws + (2u << 20));           // 8 MB (4 u64 / word)
    float* C = (float*)(ws + (10u << 20));       // 15 floats

    setup_kernel<<<1, 64, 0, stream>>>(C);
    init_bits<<<NWORDS / 16, 256, 0, stream>>>(probs, C, L, Kp);
    fused_sweeps<<<256, 256, 0, stream>>>(L, Kp, out);
}

// Round 4
// 255.779 us; speedup vs baseline: 7.9299x; 1.0376x over previous
//
#include <hip/hip_runtime.h>
#include <math.h>

#define HH 4096
#define WW 4096
#define WPR 64                  // 64-bit words per row
typedef unsigned long long u64;

#define TILE_R 128              // interior rows per block
#define HALO_R 60               // vertical halo (= #half-sweeps)
#define REG_R  248              // TILE_R + 2*HALO_R
#define REG_WC 10               // 8 interior word-cols + 1 halo each side
#define RWORDS (REG_R * REG_WC) // 2480 (= 16 waves * 155)
#define WPW_A  155              // words per wave in phase A
#define NTHR   1024
#define WPT    3                // ceil(RWORDS / NTHR)
#define NSWEEP 60

// fp64 decision, EXACTLY as the round-1 kernel that scored absmax=0.
__device__ __forceinline__ bool decision(float p, int ncnt, int ns) {
    double pd = (double)p;
    double u1 = -log(pd + 1e-6);
    double u0 = -log1p(-(pd - 1e-6));
    double cost1 = u1 + 0.5 * (double)(ncnt - ns);
    double cost0 = u0 + 0.5 * (double)ns;
    return cost1 < cost0;
}

// Binary-search minimal fp32 p where decision() is true (monotone in p).
// C[(ncnt-2)*5 + ns], 15 floats.
__global__ void setup_kernel(float* __restrict__ C) {
    int t = threadIdx.x;
    if (t >= 15) return;
    int ncnt = 2 + t / 5;
    int ns = t % 5;
    unsigned lo = 0u, hi = 0x3F800000u;   // [0.0f, 1.0f] in bit-space
    for (int it = 0; it < 32 && hi - lo > 1; ++it) {
        unsigned mid = lo + (hi - lo) / 2;
        if (decision(__uint_as_float(mid), ncnt, ns)) hi = mid; else lo = mid;
    }
    C[t] = __uint_as_float(hi);
}

// One kernel: (A) ballot-pack region from probs into LDS label bits +
// k-plane bits, (B) 60 in-place half-sweeps in LDS, (C) expand interior
// to float32 output.
__global__ __launch_bounds__(NTHR)
void fused_all(const float* __restrict__ probs, const float* __restrict__ C,
               float* __restrict__ out) {
    // SALL: [0]=labels, [1..3]=k-planes k0/k1/k2 (each RWORDS u64)
    __shared__ u64 SALL[4 * RWORDS];      // 79,360 B
    u64* const SL = SALL;

    const int tid = threadIdx.x;
    const int lane = tid & 63;
    const int wv = tid >> 6;              // 0..15
    const int tr = blockIdx.x >> 3;       // 0..31 tile row
    const int tc = blockIdx.x & 7;        // 0..7  tile col
    const int r0 = tr * TILE_R - HALO_R;  // global row of region row 0
    const int wc0 = tc * 8 - 1;           // global word-col of region col 0

    // interior thresholds (ncnt=4) hoisted
    const float c0 = C[10], c1 = C[11], c2 = C[12], c3 = C[13], c4 = C[14];

    // ---- Phase A: pack region (labels + k-planes) into LDS via ballots ----
    for (int t = 0; t < WPW_A; ++t) {
        int idx = wv + 16 * t;
        int r = idx / REG_WC;
        int c = idx - REG_WC * r;
        int g = r0 + r, wc = wc0 + c;
        u64 lb, b0, b1, b2;
        if (g >= 0 && g < HH && wc >= 0 && wc < WPR) {   // wave-uniform
            float p = probs[(size_t)g * WW + wc * 64 + lane];
            int k = (p < c0) + (p < c1) + (p < c2) + (p < c3) + (p < c4);
            bool gE0 = (g == 0), gE1 = (g == HH - 1);
            bool jE0 = (wc == 0) & (lane == 0);
            bool jE1 = (wc == WPR - 1) & (lane == 63);
            if (gE0 | gE1 | jE0 | jE1) {   // rare, divergent fixup
                int ncnt = 4 - gE0 - gE1 - jE0 - jE1;
                const float* Cr = C + (ncnt - 2) * 5;
                k = (p < Cr[0]) + (p < Cr[1]) + (p < Cr[2]) + (p < Cr[3]) + (p < Cr[4]);
            }
            lb = __ballot(p > 0.5f);
            b0 = __ballot(k & 1);
            b1 = __ballot(k & 2);
            b2 = __ballot(k & 4);
        } else {
            lb = 0ull; b0 = b1 = b2 = ~0ull;   // outside: label 0, k=7
        }
        if (lane < 4) {
            u64 v = (lane == 0) ? lb : (lane == 1) ? b0 : (lane == 2) ? b1 : b2;
            SALL[lane * RWORDS + idx] = v;
        }
    }
    __syncthreads();

    // ---- owners pull their words + k-planes into registers ----
    u64 cur[WPT], k0[WPT], k1[WPT], k2[WPT];
    int rr[WPT], cc[WPT];
#pragma unroll
    for (int m = 0; m < WPT; ++m) {
        int idx = tid + NTHR * m;
        int r = 0, c = 0;
        u64 l = 0, a = ~0ull, b = ~0ull, d = ~0ull;
        if (idx < RWORDS) {
            r = idx / REG_WC;
            c = idx - REG_WC * r;
            l = SL[idx];
            a = SALL[RWORDS + idx];
            b = SALL[2 * RWORDS + idx];
            d = SALL[3 * RWORDS + idx];
        }
        cur[m] = l; k0[m] = a; k1[m] = b; k2[m] = d;
        rr[m] = r; cc[m] = c;
    }
    __syncthreads();   // k-plane reads done before sweeps overwrite? (SK never
                       // written again; barrier orders reads vs sweep-0 SL writes)

    // ---- Phase B: 60 in-place half-sweeps ----
    for (int s = 0; s < NSWEEP; ++s) {
        const u64 flip = (s & 1) ? ~0ull : 0ull;
        const int rlo = s + 1, rhi = REG_R - 1 - s;   // trapezoid bounds
#pragma unroll
        for (int m = 0; m < WPT; ++m) {
            int idx = tid + NTHR * m;
            int r = rr[m];
            if (idx < RWORDS && r >= rlo && r < rhi) {
                int c = cc[m];
                u64 center = cur[m];
                u64 up = SL[idx - REG_WC], dn = SL[idx + REG_WC];
                u64 pw = (c > 0) ? SL[idx - 1] : 0ull;
                u64 nw = (c < REG_WC - 1) ? SL[idx + 1] : 0ull;
                u64 lv = (center << 1) | (pw >> 63);
                u64 rv = (center >> 1) | (nw << 63);
                // bit-sliced ns = up+dn+lv+rv (planes n2:n1:n0)
                u64 sxy = up ^ dn, ca = up & dn;
                u64 txy = lv ^ rv, cb = lv & rv;
                u64 n0 = sxy ^ txy, cd = sxy & txy;
                u64 n1 = ca ^ cb ^ cd;
                u64 n2 = (ca & cb) | (cd & (ca ^ cb));
                // ge = (ns >= k), 3-bit unsigned compare
                u64 ge = (n2 & ~k2[m]) |
                         (~(n2 ^ k2[m]) & ((n1 & ~k1[m]) |
                                           (~(n1 ^ k1[m]) & (n0 | ~k0[m]))));
                u64 base = ((r0 + r) & 1) ? 0xAAAAAAAAAAAAAAAAull
                                          : 0x5555555555555555ull;
                u64 mask = base ^ flip;
                u64 nv = (ge & mask) | (center & ~mask);
                cur[m] = nv;
                SL[idx] = nv;   // race-free: writes touch only parity-s bits
            }
        }
        __syncthreads();
    }

    // ---- Phase C: expand interior (128 rows x 512 bits) to float4 output ----
#pragma unroll 4
    for (int m = 0; m < 16; ++m) {
        int idx = tid + NTHR * m;          // 0..16383 float4s
        int ri = idx >> 7;                 // interior row 0..127
        int q = idx & 127;                 // float4 within row
        u64 word = SL[(HALO_R + ri) * REG_WC + 1 + (q >> 4)];
        unsigned bits = (unsigned)(word >> ((q & 15) * 4)) & 0xFu;
        float4 v;
        v.x = (float)(bits & 1u);
        v.y = (float)((bits >> 1) & 1u);
        v.z = (float)((bits >> 2) & 1u);
        v.w = (float)((bits >> 3) & 1u);
        int g = tr * TILE_R + ri;
        ((float4*)out)[(size_t)g * (WW / 4) + (wc0 + 1) * 16 + q] = v;
    }
}

extern "C" void kernel_launch(void* const* d_in, const int* in_sizes, int n_in,
                              void* d_out, int out_size, void* d_ws, size_t ws_size,
                              hipStream_t stream) {
    const float* probs = (const float*)d_in[0];
    float* out = (float*)d_out;
    float* C = (float*)d_ws;    // 15 floats

    setup_kernel<<<1, 64, 0, stream>>>(C);
    fused_all<<<256, NTHR, 0, stream>>>(probs, C, out);
}

// Round 5
// 246.155 us; speedup vs baseline: 8.2400x; 1.0391x over previous
//
#include <hip/hip_runtime.h>
#include <math.h>

#define HH 4096
#define WW 4096
#define WPR 64                  // 64-bit words per row
typedef unsigned long long u64;

#define TILE_R 128              // interior rows per block
#define HALO_R 60               // vertical halo (= #half-sweeps)
#define REG_R  248              // TILE_R + 2*HALO_R
#define REG_WC 10               // 8 interior word-cols + 1 halo each side
#define RWORDS (REG_R * REG_WC) // 2480 (= 16 waves * 155)
#define WPW_A  155              // words per wave in phase A
#define NTHR   1024
#define WPT    3                // ceil(RWORDS / NTHR)
#define NSWEEP 60

// fp64 decision, EXACTLY as the round-1 kernel that scored absmax=0.
__device__ __forceinline__ bool decision(float p, int ncnt, int ns) {
    double pd = (double)p;
    double u1 = -log(pd + 1e-6);
    double u0 = -log1p(-(pd - 1e-6));
    double cost1 = u1 + 0.5 * (double)(ncnt - ns);
    double cost0 = u0 + 0.5 * (double)ns;
    return cost1 < cost0;
}

// Single kernel:
//  (0) wave 0 binary-searches the 15 fp32 crossover constants into LDS
//  (A) ballot-pack region from probs into LDS label bits + k-plane bits
//  (B) 60 in-place half-sweeps in LDS
//  (C) expand interior to float32 output
__global__ __launch_bounds__(NTHR, 4)   // 4 waves/SIMD resident -> <=128 VGPR, no spills
void fused_all(const float* __restrict__ probs, float* __restrict__ out) {
    // SALL: [0]=labels, [1..3]=k-planes k0/k1/k2 (each RWORDS u64)
    __shared__ u64 SALL[4 * RWORDS];      // 79,360 B
    __shared__ float Cs[16];
    u64* const SL = SALL;

    const int tid = threadIdx.x;
    const int lane = tid & 63;
    const int wv = tid >> 6;              // 0..15
    const int tr = blockIdx.x >> 3;       // 0..31 tile row
    const int tc = blockIdx.x & 7;        // 0..7  tile col
    const int r0 = tr * TILE_R - HALO_R;  // global row of region row 0
    const int wc0 = tc * 8 - 1;           // global word-col of region col 0

    // ---- Phase 0: crossover constants (monotone fp64 decision => exact fp32
    // threshold). Lanes 0..14 of wave 0; ~1 us, removes a separate dispatch.
    if (tid < 15) {
        int ncnt = 2 + tid / 5;
        int ns = tid % 5;
        unsigned lo = 0u, hi = 0x3F800000u;   // [0.0f, 1.0f] in bit-space
        for (int it = 0; it < 32 && hi - lo > 1; ++it) {
            unsigned mid = lo + (hi - lo) / 2;
            if (decision(__uint_as_float(mid), ncnt, ns)) hi = mid; else lo = mid;
        }
        Cs[tid] = __uint_as_float(hi);
    }
    __syncthreads();

    // interior thresholds (ncnt=4) hoisted to registers
    const float c0 = Cs[10], c1 = Cs[11], c2 = Cs[12], c3 = Cs[13], c4 = Cs[14];

    // ---- Phase A: pack region (labels + k-planes) into LDS via ballots ----
    float pcur;
    {
        int r = wv / REG_WC, c = wv - REG_WC * r;
        int g = r0 + r, wc = wc0 + c;
        int gc = g < 0 ? 0 : (g > HH - 1 ? HH - 1 : g);
        int wcc = wc < 0 ? 0 : (wc > WPR - 1 ? WPR - 1 : wc);
        pcur = probs[(size_t)gc * WW + (size_t)wcc * 64 + lane];
    }
    for (int t = 0; t < WPW_A; ++t) {
        int idx = wv + 16 * t;
        int r = idx / REG_WC, c = idx - REG_WC * r;
        int g = r0 + r, wc = wc0 + c;
        bool valid = (g >= 0) & (g < HH) & (wc >= 0) & (wc < WPR);  // wave-uniform
        float p = pcur;
        if (t + 1 < WPW_A) {   // prefetch next iteration's row (clamped addr)
            int idx2 = idx + 16;
            int r2 = idx2 / REG_WC, c2 = idx2 - REG_WC * r2;
            int g2 = r0 + r2, wc2 = wc0 + c2;
            int gc2 = g2 < 0 ? 0 : (g2 > HH - 1 ? HH - 1 : g2);
            int wcc2 = wc2 < 0 ? 0 : (wc2 > WPR - 1 ? WPR - 1 : wc2);
            pcur = probs[(size_t)gc2 * WW + (size_t)wcc2 * 64 + lane];
        }
        u64 lb, b0, b1, b2;
        if (valid) {
            int k = (p < c0) + (p < c1) + (p < c2) + (p < c3) + (p < c4);
            bool gE0 = (g == 0), gE1 = (g == HH - 1);
            bool jE0 = (wc == 0) & (lane == 0);
            bool jE1 = (wc == WPR - 1) & (lane == 63);
            if (gE0 | gE1 | jE0 | jE1) {   // rare, divergent fixup
                int ncnt = 4 - gE0 - gE1 - jE0 - jE1;
                const float* Cr = Cs + (ncnt - 2) * 5;
                k = (p < Cr[0]) + (p < Cr[1]) + (p < Cr[2]) + (p < Cr[3]) + (p < Cr[4]);
            }
            lb = __ballot(p > 0.5f);
            b0 = __ballot(k & 1);
            b1 = __ballot(k & 2);
            b2 = __ballot(k & 4);
        } else {
            lb = 0ull; b0 = b1 = b2 = ~0ull;   // outside: label 0, k=7
        }
        if (lane < 4) {
            u64 v = (lane == 0) ? lb : (lane == 1) ? b0 : (lane == 2) ? b1 : b2;
            SALL[lane * RWORDS + idx] = v;
        }
    }
    __syncthreads();

    // ---- owners pull their words + k-planes into registers ----
    u64 cur[WPT], k0[WPT], k1[WPT], k2[WPT], basem[WPT];
    int rr[WPT], cc[WPT];
#pragma unroll
    for (int m = 0; m < WPT; ++m) {
        int idx = tid + NTHR * m;
        int r = 0, c = 0;
        u64 l = 0, a = ~0ull, b = ~0ull, d = ~0ull;
        if (idx < RWORDS) {
            r = idx / REG_WC;
            c = idx - REG_WC * r;
            l = SL[idx];
            a = SALL[RWORDS + idx];
            b = SALL[2 * RWORDS + idx];
            d = SALL[3 * RWORDS + idx];
        }
        cur[m] = l; k0[m] = a; k1[m] = b; k2[m] = d;
        rr[m] = r; cc[m] = c;
        basem[m] = ((r0 + r) & 1) ? 0xAAAAAAAAAAAAAAAAull
                                  : 0x5555555555555555ull;
    }
    __syncthreads();   // k-plane reads ordered before sweep-0 SL writes

    // ---- Phase B: 60 in-place half-sweeps ----
    for (int s = 0; s < NSWEEP; ++s) {
        const u64 flip = (s & 1) ? ~0ull : 0ull;
        const int rlo = s + 1, rhi = REG_R - 1 - s;   // trapezoid bounds
#pragma unroll
        for (int m = 0; m < WPT; ++m) {
            int idx = tid + NTHR * m;
            int r = rr[m];
            if (idx < RWORDS && r >= rlo && r < rhi) {
                int c = cc[m];
                u64 center = cur[m];
                u64 up = SL[idx - REG_WC], dn = SL[idx + REG_WC];
                u64 pw = (c > 0) ? SL[idx - 1] : 0ull;
                u64 nw = (c < REG_WC - 1) ? SL[idx + 1] : 0ull;
                u64 lv = (center << 1) | (pw >> 63);
                u64 rv = (center >> 1) | (nw << 63);
                // bit-sliced ns = up+dn+lv+rv (planes n2:n1:n0)
                u64 sxy = up ^ dn, ca = up & dn;
                u64 txy = lv ^ rv, cb = lv & rv;
                u64 n0 = sxy ^ txy, cd = sxy & txy;
                u64 n1 = ca ^ cb ^ cd;
                u64 n2 = (ca & cb) | (cd & (ca ^ cb));
                // ge = (ns >= k), 3-bit unsigned compare
                u64 ge = (n2 & ~k2[m]) |
                         (~(n2 ^ k2[m]) & ((n1 & ~k1[m]) |
                                           (~(n1 ^ k1[m]) & (n0 | ~k0[m]))));
                u64 mask = basem[m] ^ flip;
                u64 nv = (ge & mask) | (center & ~mask);
                cur[m] = nv;
                SL[idx] = nv;   // race-free: writes touch only parity-s bits
            }
        }
        __syncthreads();
    }

    // ---- Phase C: expand interior (128 rows x 512 bits) to float4 output ----
#pragma unroll 4
    for (int m = 0; m < 16; ++m) {
        int idx = tid + NTHR * m;          // 0..16383 float4s
        int ri = idx >> 7;                 // interior row 0..127
        int q = idx & 127;                 // float4 within row
        u64 word = SL[(HALO_R + ri) * REG_WC + 1 + (q >> 4)];
        unsigned bits = (unsigned)(word >> ((q & 15) * 4)) & 0xFu;
        float4 v;
        v.x = (float)(bits & 1u);
        v.y = (float)((bits >> 1) & 1u);
        v.z = (float)((bits >> 2) & 1u);
        v.w = (float)((bits >> 3) & 1u);
        int g = tr * TILE_R + ri;
        ((float4*)out)[(size_t)g * (WW / 4) + (wc0 + 1) * 16 + q] = v;
    }
}

extern "C" void kernel_launch(void* const* d_in, const int* in_sizes, int n_in,
                              void* d_out, int out_size, void* d_ws, size_t ws_size,
                              hipStream_t stream) {
    const float* probs = (const float*)d_in[0];
    float* out = (float*)d_out;
    fused_all<<<256, NTHR, 0, stream>>>(probs, out);
}

// Round 6
// 155.407 us; speedup vs baseline: 13.0516x; 1.5839x over previous
//
#include <hip/hip_runtime.h>
#include <math.h>

#define HH 4096
#define WW 4096
#define WPR 64                  // 64-bit words per row
#define NWORDS (HH * WPR)       // 262144
typedef unsigned long long u64;

#define TILE_R 128              // interior rows per block
#define HALO_R 60               // vertical halo (= #half-sweeps)
#define REG_R  248              // TILE_R + 2*HALO_R
#define REG_WC 10               // 8 interior word-cols + 1 halo each side
#define RWORDS (REG_R * REG_WC) // 2480
#define NTHR   1024
#define WPT    3                // ceil(RWORDS / NTHR)
#define NSWEEP 60

// fp64 decision, EXACTLY as the round-1 kernel that scored absmax=0.
__device__ __forceinline__ bool decision(float p, int ncnt, int ns) {
    double pd = (double)p;
    double u1 = -log(pd + 1e-6);
    double u0 = -log1p(-(pd - 1e-6));
    double cost1 = u1 + 0.5 * (double)(ncnt - ns);
    double cost0 = u0 + 0.5 * (double)ns;
    return cost1 < cost0;
}

// Binary-search minimal fp32 p where decision() is true (monotone in p).
__global__ void setup_kernel(float* __restrict__ C) {
    int t = threadIdx.x;
    if (t >= 15) return;
    int ncnt = 2 + t / 5;
    int ns = t % 5;
    unsigned lo = 0u, hi = 0x3F800000u;   // [0.0f, 1.0f] in bit-space
    for (int it = 0; it < 32 && hi - lo > 1; ++it) {
        unsigned mid = lo + (hi - lo) / 2;
        if (decision(__uint_as_float(mid), ncnt, ns)) hi = mid; else lo = mid;
    }
    C[t] = __uint_as_float(hi);
}

// Pack labels + k-plane bits (SoA) for the whole grid. 4 words/wave,
// loads batched up front (no early return, exact grid).
__global__ __launch_bounds__(256)
void pack_kernel(const float* __restrict__ probs, const float* __restrict__ C,
                 u64* __restrict__ L, u64* __restrict__ K0,
                 u64* __restrict__ K1, u64* __restrict__ K2) {
    int gwave = (blockIdx.x * 256 + threadIdx.x) >> 6;
    int lane = threadIdx.x & 63;
    int w0 = gwave * 4;
    float p[4];
#pragma unroll
    for (int q = 0; q < 4; ++q)
        p[q] = probs[((size_t)(w0 + q) << 6) + lane];
    const float c0 = C[10], c1 = C[11], c2 = C[12], c3 = C[13], c4 = C[14];
#pragma unroll
    for (int q = 0; q < 4; ++q) {
        int w = w0 + q;
        int i = w >> 6;                  // row
        int jbase = (w & 63) << 6;       // column of lane 0
        float pp = p[q];
        int k = (pp < c0) + (pp < c1) + (pp < c2) + (pp < c3) + (pp < c4);
        bool gE0 = (i == 0), gE1 = (i == HH - 1);
        bool jE0 = (jbase == 0) & (lane == 0);
        bool jE1 = (jbase == WW - 64) & (lane == 63);
        if (gE0 | gE1 | jE0 | jE1) {     // rare, divergent border fixup
            int ncnt = 4 - gE0 - gE1 - jE0 - jE1;
            const float* Cr = C + (ncnt - 2) * 5;
            k = (pp < Cr[0]) + (pp < Cr[1]) + (pp < Cr[2]) + (pp < Cr[3]) + (pp < Cr[4]);
        }
        u64 lb = __ballot(pp > 0.5f);
        u64 b0 = __ballot(k & 1);
        u64 b1 = __ballot(k & 2);
        u64 b2 = __ballot(k & 4);
        if (lane == 0)      L[w]  = lb;
        else if (lane == 1) K0[w] = b0;
        else if (lane == 2) K1[w] = b1;
        else if (lane == 3) K2[w] = b2;
    }
}

// Fused: (A) load packed region (labels->LDS+regs, k-planes->regs only),
// (B) 60 in-place half-sweeps with convergence early-exit, (C) expand.
__global__ __launch_bounds__(NTHR, 4)
void fused_all(const u64* __restrict__ Lg, const u64* __restrict__ K0g,
               const u64* __restrict__ K1g, const u64* __restrict__ K2g,
               float* __restrict__ out) {
    __shared__ u64 SL[RWORDS];           // 19,840 B (labels only)
    __shared__ int chg[2];               // change flags, ping-pong by sweep parity

    const int tid = threadIdx.x;
    const int lane = tid & 63;
    const int tr = blockIdx.x >> 3;      // 0..31 tile row
    const int tc = blockIdx.x & 7;       // 0..7  tile col
    const int r0 = tr * TILE_R - HALO_R; // global row of region row 0
    const int wc0 = tc * 8 - 1;          // global word-col of region col 0

    if (tid < 2) chg[tid] = 0;

    // ---- Phase A: direct u64 loads; k-planes live ONLY in registers ----
    u64 cur[WPT], k0[WPT], k1[WPT], k2[WPT], basem[WPT];
    int rr[WPT], cc[WPT];
#pragma unroll
    for (int m = 0; m < WPT; ++m) {
        int idx = tid + NTHR * m;
        int r = 0, c = 0;
        u64 l = 0, a = ~0ull, b = ~0ull, d = ~0ull;   // outside: label 0, k=7
        if (idx < RWORDS) {
            r = idx / REG_WC;
            c = idx - REG_WC * r;
            int g = r0 + r, wc = wc0 + c;
            if (g >= 0 && g < HH && wc >= 0 && wc < WPR) {
                size_t w = (size_t)g * WPR + wc;
                l = Lg[w]; a = K0g[w]; b = K1g[w]; d = K2g[w];
            }
            SL[idx] = l;
        }
        cur[m] = l; k0[m] = a; k1[m] = b; k2[m] = d;
        rr[m] = r; cc[m] = c;
        basem[m] = ((r0 + r) & 1) ? 0xAAAAAAAAAAAAAAAAull
                                  : 0x5555555555555555ull;
    }
    __syncthreads();

    // ---- Phase B: in-place half-sweeps + convergence early-exit.
    // If two consecutive half-sweeps change nothing, all later sweeps are
    // identity (fixed point; trapezoids only shrink) -> break, bit-exact.
    int prevf = 1;
    for (int s = 0; s < NSWEEP; ++s) {
        if (tid == 0) chg[(s + 1) & 1] = 0;   // clear next slot (value already consumed)
        const u64 flip = (s & 1) ? ~0ull : 0ull;
        const int rlo = s + 1, rhi = REG_R - 1 - s;   // trapezoid bounds
        u64 chacc = 0;
#pragma unroll
        for (int m = 0; m < WPT; ++m) {
            int idx = tid + NTHR * m;
            int r = rr[m];
            if (idx < RWORDS && r >= rlo && r < rhi) {
                int c = cc[m];
                u64 center = cur[m];
                u64 up = SL[idx - REG_WC], dn = SL[idx + REG_WC];
                u64 pw = (c > 0) ? SL[idx - 1] : 0ull;
                u64 nw = (c < REG_WC - 1) ? SL[idx + 1] : 0ull;
                u64 lv = (center << 1) | (pw >> 63);
                u64 rv = (center >> 1) | (nw << 63);
                // bit-sliced ns = up+dn+lv+rv (planes n2:n1:n0)
                u64 sxy = up ^ dn, ca = up & dn;
                u64 txy = lv ^ rv, cb = lv & rv;
                u64 n0 = sxy ^ txy, cd = sxy & txy;
                u64 n1 = ca ^ cb ^ cd;
                u64 n2 = (ca & cb) | (cd & (ca ^ cb));
                // ge = (ns >= k), 3-bit unsigned compare
                u64 ge = (n2 & ~k2[m]) |
                         (~(n2 ^ k2[m]) & ((n1 & ~k1[m]) |
                                           (~(n1 ^ k1[m]) & (n0 | ~k0[m]))));
                u64 mask = basem[m] ^ flip;
                u64 nv = (ge & mask) | (center & ~mask);   // BFI
                chacc |= nv ^ center;
                cur[m] = nv;
                SL[idx] = nv;   // race-free: writes touch only parity-s bits
            }
        }
        if (__ballot(chacc != 0) != 0ull) {
            if (lane == 0) chg[s & 1] = 1;    // benign race, all write 1
        }
        __syncthreads();
        int curf = chg[s & 1];
        if (prevf == 0 && curf == 0) break;   // block-uniform decision
        prevf = curf;
    }

    // ---- Phase C: expand interior (128 rows x 512 bits) to float4 output ----
#pragma unroll 4
    for (int m = 0; m < 16; ++m) {
        int idx = tid + NTHR * m;          // 0..16383 float4s
        int ri = idx >> 7;                 // interior row 0..127
        int q = idx & 127;                 // float4 within row
        u64 word = SL[(HALO_R + ri) * REG_WC + 1 + (q >> 4)];
        unsigned bits = (unsigned)(word >> ((q & 15) * 4)) & 0xFu;
        float4 v;
        v.x = (float)(bits & 1u);
        v.y = (float)((bits >> 1) & 1u);
        v.z = (float)((bits >> 2) & 1u);
        v.w = (float)((bits >> 3) & 1u);
        int g = tr * TILE_R + ri;
        ((float4*)out)[(size_t)g * (WW / 4) + (wc0 + 1) * 16 + q] = v;
    }
}

extern "C" void kernel_launch(void* const* d_in, const int* in_sizes, int n_in,
                              void* d_out, int out_size, void* d_ws, size_t ws_size,
                              hipStream_t stream) {
    const float* probs = (const float*)d_in[0];
    float* out = (float*)d_out;
    char* ws = (char*)d_ws;
    float* C = (float*)ws;                          // 15 floats
    u64* L  = (u64*)(ws + (1u << 20));              // 2 MB
    u64* K0 = (u64*)(ws + (3u << 20));              // 2 MB
    u64* K1 = (u64*)(ws + (5u << 20));              // 2 MB
    u64* K2 = (u64*)(ws + (7u << 20));              // 2 MB

    setup_kernel<<<1, 64, 0, stream>>>(C);
    pack_kernel<<<NWORDS / 16, 256, 0, stream>>>(probs, C, L, K0, K1, K2);
    fused_all<<<256, NTHR, 0, stream>>>(L, K0, K1, K2, out);
}

// Round 7
// 152.720 us; speedup vs baseline: 13.2812x; 1.0176x over previous
//
#include <hip/hip_runtime.h>
#include <math.h>

#define HH 4096
#define WW 4096
#define WPR 64                  // 64-bit words per row
#define NWORDS (HH * WPR)       // 262144
typedef unsigned long long u64;

#define TILE_R 128              // interior rows per block
#define HALO_R 60               // vertical halo (= #half-sweeps)
#define REG_R  248              // TILE_R + 2*HALO_R
#define REG_WC 10               // 8 interior word-cols + 1 halo each side
#define RWORDS (REG_R * REG_WC) // 2480
#define NTHR   1024
#define WPT    3                // ceil(RWORDS / NTHR)
#define NSWEEP 60
#define PACK_WPW 8              // words per wave in pack kernel

// fp64 decision, EXACTLY as the round-1 kernel that scored absmax=0.
__device__ __forceinline__ bool decision(float p, int ncnt, int ns) {
    double pd = (double)p;
    double u1 = -log(pd + 1e-6);
    double u0 = -log1p(-(pd - 1e-6));
    double cost1 = u1 + 0.5 * (double)(ncnt - ns);
    double cost0 = u0 + 0.5 * (double)ns;
    return cost1 < cost0;
}

// Binary-search minimal fp32 p where decision() is true (monotone in p).
__global__ void setup_kernel(float* __restrict__ C) {
    int t = threadIdx.x;
    if (t >= 15) return;
    int ncnt = 2 + t / 5;
    int ns = t % 5;
    unsigned lo = 0u, hi = 0x3F800000u;   // [0.0f, 1.0f] in bit-space
    for (int it = 0; it < 32 && hi - lo > 1; ++it) {
        unsigned mid = lo + (hi - lo) / 2;
        if (decision(__uint_as_float(mid), ncnt, ns)) hi = mid; else lo = mid;
    }
    C[t] = __uint_as_float(hi);
}

// Pack labels + k-plane bits (SoA). 8 words/wave, loads batched up front.
__global__ __launch_bounds__(256)
void pack_kernel(const float* __restrict__ probs, const float* __restrict__ C,
                 u64* __restrict__ L, u64* __restrict__ K0,
                 u64* __restrict__ K1, u64* __restrict__ K2) {
    int gwave = (blockIdx.x * 256 + threadIdx.x) >> 6;
    int lane = threadIdx.x & 63;
    int w0 = gwave * PACK_WPW;
    float p[PACK_WPW];
#pragma unroll
    for (int q = 0; q < PACK_WPW; ++q)
        p[q] = probs[((size_t)(w0 + q) << 6) + lane];
    const float c0 = C[10], c1 = C[11], c2 = C[12], c3 = C[13], c4 = C[14];
#pragma unroll
    for (int q = 0; q < PACK_WPW; ++q) {
        int w = w0 + q;
        int i = w >> 6;                  // row
        int jbase = (w & 63) << 6;       // column of lane 0
        float pp = p[q];
        int k = (pp < c0) + (pp < c1) + (pp < c2) + (pp < c3) + (pp < c4);
        bool gE0 = (i == 0), gE1 = (i == HH - 1);
        bool jE0 = (jbase == 0) & (lane == 0);
        bool jE1 = (jbase == WW - 64) & (lane == 63);
        if (gE0 | gE1 | jE0 | jE1) {     // rare, divergent border fixup
            int ncnt = 4 - gE0 - gE1 - jE0 - jE1;
            const float* Cr = C + (ncnt - 2) * 5;
            k = (pp < Cr[0]) + (pp < Cr[1]) + (pp < Cr[2]) + (pp < Cr[3]) + (pp < Cr[4]);
        }
        u64 lb = __ballot(pp > 0.5f);
        u64 b0 = __ballot(k & 1);
        u64 b1 = __ballot(k & 2);
        u64 b2 = __ballot(k & 4);
        if (lane == 0)      L[w]  = lb;
        else if (lane == 1) K0[w] = b0;
        else if (lane == 2) K1[w] = b1;
        else if (lane == 3) K2[w] = b2;
    }
}

// Fused: (A) load packed region (labels->LDS+regs, k-planes->regs only),
// (B) up-to-60 in-place half-sweeps with convergence early-exit, (C) expand.
// waves_per_eu(4,4): exactly 4 waves/EU (the max possible for a 1024-thread
// block at 1 block/CU) -> allocator may use up to 128 VGPRs, no k-plane spill.
__global__ __attribute__((amdgpu_flat_work_group_size(NTHR, NTHR),
                          amdgpu_waves_per_eu(4, 4)))
void fused_all(const u64* __restrict__ Lg, const u64* __restrict__ K0g,
               const u64* __restrict__ K1g, const u64* __restrict__ K2g,
               float* __restrict__ out) {
    __shared__ u64 SL[RWORDS];           // 19,840 B (labels only)
    __shared__ int chg[3];               // change flags, slot = sweep % 3

    const int tid = threadIdx.x;
    const int lane = tid & 63;
    const int tr = blockIdx.x >> 3;      // 0..31 tile row
    const int tc = blockIdx.x & 7;       // 0..7  tile col
    const int r0 = tr * TILE_R - HALO_R; // global row of region row 0
    const int wc0 = tc * 8 - 1;          // global word-col of region col 0

    if (tid < 3) chg[tid] = 0;

    // ---- Phase A: direct u64 loads; k-planes live ONLY in registers ----
    u64 cur[WPT], k0[WPT], k1[WPT], k2[WPT], basem[WPT];
    int rr[WPT], cc[WPT];
#pragma unroll
    for (int m = 0; m < WPT; ++m) {
        int idx = tid + NTHR * m;
        int r = 0, c = 0;
        u64 l = 0, a = ~0ull, b = ~0ull, d = ~0ull;   // outside: label 0, k=7
        if (idx < RWORDS) {
            r = idx / REG_WC;
            c = idx - REG_WC * r;
            int g = r0 + r, wc = wc0 + c;
            if (g >= 0 && g < HH && wc >= 0 && wc < WPR) {
                size_t w = (size_t)g * WPR + wc;
                l = Lg[w]; a = K0g[w]; b = K1g[w]; d = K2g[w];
            }
            SL[idx] = l;
        }
        cur[m] = l; k0[m] = a; k1[m] = b; k2[m] = d;
        rr[m] = r; cc[m] = c;
        basem[m] = ((r0 + r) & 1) ? 0xAAAAAAAAAAAAAAAAull
                                  : 0x5555555555555555ull;
    }
    __syncthreads();

    // ---- Phase B: in-place half-sweeps + convergence early-exit.
    // Two consecutive no-change half-sweeps => fixed point; since later
    // trapezoids are subsets updated by the same rule on the same state,
    // all later sweeps are identity -> break, bit-exact.
    // chg slots are mod-3: the clear of slot (s+1)%3 at sweep s is separated
    // by the sweep-(s-1) barrier from its last readers (at sweep s-2).
    int prevf = 1;
    for (int s = 0; s < NSWEEP; ++s) {
        if (tid == 0) chg[(s + 1) % 3] = 0;
        const u64 flip = (s & 1) ? ~0ull : 0ull;
        const int rlo = s + 1, rhi = REG_R - 1 - s;   // trapezoid bounds
        u64 chacc = 0;
#pragma unroll
        for (int m = 0; m < WPT; ++m) {
            int idx = tid + NTHR * m;
            int r = rr[m];
            if (idx < RWORDS && r >= rlo && r < rhi) {
                int c = cc[m];
                u64 center = cur[m];
                u64 up = SL[idx - REG_WC], dn = SL[idx + REG_WC];
                u64 pw = (c > 0) ? SL[idx - 1] : 0ull;
                u64 nw = (c < REG_WC - 1) ? SL[idx + 1] : 0ull;
                u64 lv = (center << 1) | (pw >> 63);
                u64 rv = (center >> 1) | (nw << 63);
                // bit-sliced ns = up+dn+lv+rv (planes n2:n1:n0)
                u64 sxy = up ^ dn, ca = up & dn;
                u64 txy = lv ^ rv, cb = lv & rv;
                u64 n0 = sxy ^ txy, cd = sxy & txy;
                u64 n1 = ca ^ cb ^ cd;
                u64 n2 = (ca & cb) | (cd & (ca ^ cb));
                // ge = (ns >= k), 3-bit unsigned compare
                u64 ge = (n2 & ~k2[m]) |
                         (~(n2 ^ k2[m]) & ((n1 & ~k1[m]) |
                                           (~(n1 ^ k1[m]) & (n0 | ~k0[m]))));
                u64 mask = basem[m] ^ flip;
                u64 nv = (ge & mask) | (center & ~mask);   // BFI
                chacc |= nv ^ center;
                cur[m] = nv;
                SL[idx] = nv;   // race-free: writes touch only parity-s bits
            }
        }
        if (__ballot(chacc != 0) != 0ull) {
            if (lane == 0) chg[s % 3] = 1;    // benign race, all write 1
        }
        __syncthreads();
        int curf = chg[s % 3];
        if (prevf == 0 && curf == 0) break;   // block-uniform decision
        prevf = curf;
    }

    // ---- Phase C: expand interior (128 rows x 512 bits) to float4 output ----
#pragma unroll 4
    for (int m = 0; m < 16; ++m) {
        int idx = tid + NTHR * m;          // 0..16383 float4s
        int ri = idx >> 7;                 // interior row 0..127
        int q = idx & 127;                 // float4 within row
        u64 word = SL[(HALO_R + ri) * REG_WC + 1 + (q >> 4)];
        unsigned bits = (unsigned)(word >> ((q & 15) * 4)) & 0xFu;
        float4 v;
        v.x = (float)(bits & 1u);
        v.y = (float)((bits >> 1) & 1u);
        v.z = (float)((bits >> 2) & 1u);
        v.w = (float)((bits >> 3) & 1u);
        int g = tr * TILE_R + ri;
        ((float4*)out)[(size_t)g * (WW / 4) + (wc0 + 1) * 16 + q] = v;
    }
}

extern "C" void kernel_launch(void* const* d_in, const int* in_sizes, int n_in,
                              void* d_out, int out_size, void* d_ws, size_t ws_size,
                              hipStream_t stream) {
    const float* probs = (const float*)d_in[0];
    float* out = (float*)d_out;
    char* ws = (char*)d_ws;
    float* C = (float*)ws;                          // 15 floats
    u64* L  = (u64*)(ws + (1u << 20));              // 2 MB
    u64* K0 = (u64*)(ws + (3u << 20));              // 2 MB
    u64* K1 = (u64*)(ws + (5u << 20));              // 2 MB
    u64* K2 = (u64*)(ws + (7u << 20));              // 2 MB

    setup_kernel<<<1, 64, 0, stream>>>(C);
    pack_kernel<<<NWORDS / (PACK_WPW * 4), 256, 0, stream>>>(probs, C, L, K0, K1, K2);
    fused_all<<<256, NTHR, 0, stream>>>(L, K0, K1, K2, out);
}

// Round 8
// 138.281 us; speedup vs baseline: 14.6680x; 1.1044x over previous
//
#include <hip/hip_runtime.h>
#include <math.h>

#define HH 4096
#define WW 4096
#define WPR 64                  // 64-bit words per row
#define NWORDS (HH * WPR)       // 262144
typedef unsigned long long u64;

#define TILE_R 128              // interior rows per block
#define HALO_R 60               // vertical halo (= #half-sweeps)
#define REG_R  248              // TILE_R + 2*HALO_R
#define REG_WC 10               // 8 interior word-cols + 1 halo each side
#define RWORDS (REG_R * REG_WC) // 2480
#define NTHR   1024
#define WPT    3                // ceil(RWORDS / NTHR)
#define NSWEEP 60
#define PACK_WPW 16             // words per wave in pack kernel

// fp64 decision, EXACTLY as the round-1 kernel that scored absmax=0.
__device__ __forceinline__ bool decision(float p, int ncnt, int ns) {
    double pd = (double)p;
    double u1 = -log(pd + 1e-6);
    double u0 = -log1p(-(pd - 1e-6));
    double cost1 = u1 + 0.5 * (double)(ncnt - ns);
    double cost0 = u0 + 0.5 * (double)ns;
    return cost1 < cost0;
}

// Minimal fp32 p with decision()==true (decision is monotone in p).
// Analytic seed + decision()-verified bracket + short binary search:
// exact by construction (every boundary test uses decision() itself).
__global__ void setup_kernel(float* __restrict__ C) {
    int t = threadIdx.x;
    if (t >= 15) return;
    int ncnt = 2 + t / 5;
    int ns = t % 5;
    // crossover of f(p)=log((1-p+1e-6)/(p+1e-6)) against T=0.5*(2ns-ncnt)
    double T = 0.5 * (double)(2 * ns - ncnt);
    double eT = exp(T);
    double p0 = (1.0 + 1e-6 - 1e-6 * eT) / (1.0 + eT);
    float f0 = (float)p0;
    if (f0 < 0.0f) f0 = 0.0f;
    if (f0 > 1.0f) f0 = 1.0f;
    unsigned b0 = __float_as_uint(f0);
    unsigned lo = (b0 > 64u) ? b0 - 64u : 0u;
    unsigned hi = (b0 + 64u < 0x3F800000u) ? b0 + 64u : 0x3F800000u;
    // verify bracket with the exact decision; fall back to full range
    if (decision(__uint_as_float(lo), ncnt, ns)) lo = 0u;            // need false at lo
    if (!decision(__uint_as_float(hi), ncnt, ns)) hi = 0x3F800000u;  // need true at hi
    while (hi - lo > 1u) {
        unsigned mid = lo + (hi - lo) / 2u;
        if (decision(__uint_as_float(mid), ncnt, ns)) hi = mid; else lo = mid;
    }
    C[t] = __uint_as_float(hi);
}

// Pack labels + k-planes AoS: Kp[4w+0..3] = (L, k0, k1, k2), 32B-aligned.
__global__ __launch_bounds__(256)
void pack_kernel(const float* __restrict__ probs, const float* __restrict__ C,
                 u64* __restrict__ Kp) {
    int gwave = (blockIdx.x * 256 + threadIdx.x) >> 6;
    int lane = threadIdx.x & 63;
    int w0 = gwave * PACK_WPW;
    float p[PACK_WPW];
#pragma unroll
    for (int q = 0; q < PACK_WPW; ++q)
        p[q] = probs[((size_t)(w0 + q) << 6) + lane];
    const float c0 = C[10], c1 = C[11], c2 = C[12], c3 = C[13], c4 = C[14];
#pragma unroll
    for (int q = 0; q < PACK_WPW; ++q) {
        int w = w0 + q;
        int i = w >> 6;                  // row
        int jbase = (w & 63) << 6;       // column of lane 0
        float pp = p[q];
        int k = (pp < c0) + (pp < c1) + (pp < c2) + (pp < c3) + (pp < c4);
        bool gE0 = (i == 0), gE1 = (i == HH - 1);
        bool jE0 = (jbase == 0) & (lane == 0);
        bool jE1 = (jbase == WW - 64) & (lane == 63);
        if (gE0 | gE1 | jE0 | jE1) {     // rare, divergent border fixup
            int ncnt = 4 - gE0 - gE1 - jE0 - jE1;
            const float* Cr = C + (ncnt - 2) * 5;
            k = (pp < Cr[0]) + (pp < Cr[1]) + (pp < Cr[2]) + (pp < Cr[3]) + (pp < Cr[4]);
        }
        u64 lb = __ballot(pp > 0.5f);
        u64 b0 = __ballot(k & 1);
        u64 b1 = __ballot(k & 2);
        u64 b2 = __ballot(k & 4);
        if (lane < 4) {
            u64 v = (lane == 0) ? lb : (lane == 1) ? b0 : (lane == 2) ? b1 : b2;
            Kp[4ull * w + lane] = v;
        }
    }
}

// Fused: (A) load packed region via b128 pairs (labels->LDS+regs, k-planes
// ->regs only), (B) half-sweeps with convergence early-exit, (C) expand.
__global__ __attribute__((amdgpu_flat_work_group_size(NTHR, NTHR),
                          amdgpu_waves_per_eu(4, 4)))
void fused_all(const u64* __restrict__ Kp, float* __restrict__ out) {
    __shared__ u64 SL[RWORDS];           // 19,840 B (labels only)
    __shared__ int chg[3];               // change flags, slot = sweep % 3

    const int tid = threadIdx.x;
    const int lane = tid & 63;
    const int tr = blockIdx.x >> 3;      // 0..31 tile row
    const int tc = blockIdx.x & 7;       // 0..7  tile col
    const int r0 = tr * TILE_R - HALO_R; // global row of region row 0
    const int wc0 = tc * 8 - 1;          // global word-col of region col 0

    if (tid < 3) chg[tid] = 0;

    // ---- Phase A: two ulonglong2 loads per word; k-planes in regs only ----
    const ulonglong2* Kp2 = (const ulonglong2*)Kp;
    u64 cur[WPT], k0[WPT], k1[WPT], k2[WPT], basem[WPT];
    int rr[WPT], cc[WPT];
#pragma unroll
    for (int m = 0; m < WPT; ++m) {
        int idx = tid + NTHR * m;
        int r = 0, c = 0;
        u64 l = 0, a = ~0ull, b = ~0ull, d = ~0ull;   // outside: label 0, k=7
        if (idx < RWORDS) {
            r = idx / REG_WC;
            c = idx - REG_WC * r;
            int g = r0 + r, wc = wc0 + c;
            if (g >= 0 && g < HH && wc >= 0 && wc < WPR) {
                size_t w = (size_t)g * WPR + wc;
                ulonglong2 x = Kp2[2 * w];       // (L, k0)
                ulonglong2 y = Kp2[2 * w + 1];   // (k1, k2)
                l = x.x; a = x.y; b = y.x; d = y.y;
            }
            SL[idx] = l;
        }
        cur[m] = l; k0[m] = a; k1[m] = b; k2[m] = d;
        rr[m] = r; cc[m] = c;
        basem[m] = ((r0 + r) & 1) ? 0xAAAAAAAAAAAAAAAAull
                                  : 0x5555555555555555ull;
    }
    __syncthreads();

    // ---- Phase B: in-place half-sweeps + convergence early-exit.
    // Two consecutive no-change half-sweeps => fixed point; later trapezoids
    // are subsets updated by the same rule -> identity -> break, bit-exact.
    // chg slots mod-3: clear of slot (s+1)%3 at sweep s is separated from its
    // last readers (sweep s-2) by the sweep-(s-1) barrier.
    int prevf = 1;
    for (int s = 0; s < NSWEEP; ++s) {
        if (tid == 0) chg[(s + 1) % 3] = 0;
        const u64 flip = (s & 1) ? ~0ull : 0ull;
        const int rlo = s + 1, rhi = REG_R - 1 - s;   // trapezoid bounds
        u64 chacc = 0;
#pragma unroll
        for (int m = 0; m < WPT; ++m) {
            int idx = tid + NTHR * m;
            int r = rr[m];
            if (idx < RWORDS && r >= rlo && r < rhi) {
                int c = cc[m];
                u64 center = cur[m];
                u64 up = SL[idx - REG_WC], dn = SL[idx + REG_WC];
                u64 pw = (c > 0) ? SL[idx - 1] : 0ull;
                u64 nw = (c < REG_WC - 1) ? SL[idx + 1] : 0ull;
                u64 lv = (center << 1) | (pw >> 63);
                u64 rv = (center >> 1) | (nw << 63);
                // bit-sliced ns = up+dn+lv+rv (planes n2:n1:n0)
                u64 sxy = up ^ dn, ca = up & dn;
                u64 txy = lv ^ rv, cb = lv & rv;
                u64 n0 = sxy ^ txy, cd = sxy & txy;
                u64 n1 = ca ^ cb ^ cd;
                u64 n2 = (ca & cb) | (cd & (ca ^ cb));
                // ge = (ns >= k), 3-bit unsigned compare
                u64 ge = (n2 & ~k2[m]) |
                         (~(n2 ^ k2[m]) & ((n1 & ~k1[m]) |
                                           (~(n1 ^ k1[m]) & (n0 | ~k0[m]))));
                u64 mask = basem[m] ^ flip;
                u64 nv = (ge & mask) | (center & ~mask);   // BFI
                chacc |= nv ^ center;
                cur[m] = nv;
                SL[idx] = nv;   // race-free: writes touch only parity-s bits
            }
        }
        if (__ballot(chacc != 0) != 0ull) {
            if (lane == 0) chg[s % 3] = 1;    // benign race, all write 1
        }
        __syncthreads();
        int curf = chg[s % 3];
        if (prevf == 0 && curf == 0) break;   // block-uniform decision
        prevf = curf;
    }

    // ---- Phase C: expand interior (128 rows x 512 bits) to float4 output ----
#pragma unroll 4
    for (int m = 0; m < 16; ++m) {
        int idx = tid + NTHR * m;          // 0..16383 float4s
        int ri = idx >> 7;                 // interior row 0..127
        int q = idx & 127;                 // float4 within row
        u64 word = SL[(HALO_R + ri) * REG_WC + 1 + (q >> 4)];
        unsigned bits = (unsigned)(word >> ((q & 15) * 4)) & 0xFu;
        float4 v;
        v.x = (float)(bits & 1u);
        v.y = (float)((bits >> 1) & 1u);
        v.z = (float)((bits >> 2) & 1u);
        v.w = (float)((bits >> 3) & 1u);
        int g = tr * TILE_R + ri;
        ((float4*)out)[(size_t)g * (WW / 4) + (wc0 + 1) * 16 + q] = v;
    }
}

extern "C" void kernel_launch(void* const* d_in, const int* in_sizes, int n_in,
                              void* d_out, int out_size, void* d_ws, size_t ws_size,
                              hipStream_t stream) {
    const float* probs = (const float*)d_in[0];
    float* out = (float*)d_out;
    char* ws = (char*)d_ws;
    float* C = (float*)ws;                          // 15 floats
    u64* Kp = (u64*)(ws + (1u << 20));              // 8 MB AoS (L,k0,k1,k2)

    setup_kernel<<<1, 64, 0, stream>>>(C);
    pack_kernel<<<NWORDS / (PACK_WPW * 4), 256, 0, stream>>>(probs, C, Kp);
    fused_all<<<256, NTHR, 0, stream>>>(Kp, out);
}